// Round 1
// baseline (4818.755 us; speedup 1.0000x reference)
//
#include <hip/hip_runtime.h>

// ---------------------------------------------------------------------------
// VQ-VAE forward: H=256, D=64, K=512, STEPS=4, B=16, T=32768, KS=3 (fp32)
// ---------------------------------------------------------------------------

__device__ __forceinline__ int swz(int u) { return u + ((u >> 5) << 2); }

// ---------------- enc0: Ci=1, stride 2, k=3, ReLU ----------------
__global__ __launch_bounds__(256)
void enc0_kernel(const float* __restrict__ x, const float* __restrict__ w,
                 const float* __restrict__ bias, float* __restrict__ y, int T) {
  const int To = T >> 1;
  const int b = blockIdx.z, co = blockIdx.y;
  const int t = (blockIdx.x * 256 + threadIdx.x) * 4;
  const float* xb = x + (size_t)b * T;
  const float w0 = w[co * 3 + 0], w1 = w[co * 3 + 1], w2 = w[co * 3 + 2];
  const float bv = bias[co];
  float v[4];
#pragma unroll
  for (int j = 0; j < 4; j++) {
    const int tt = t + j;
    const int ti = 2 * tt - 1;
    const float a = (ti >= 0) ? xb[ti] : 0.f;
    v[j] = fmaxf(fmaf(w0, a, fmaf(w1, xb[ti + 1], fmaf(w2, xb[ti + 2], bv))), 0.f);
  }
  *(float4*)(y + ((size_t)b * 256 + co) * To + t) = make_float4(v[0], v[1], v[2], v[3]);
}

// ---------------- big conv: Ci=256, Co=256, stride 2, k=3 ----------------
// tile 128co x 128t, 256 threads, 8x8 per thread. Even/odd x decomposition:
// y[t] = w0*x[2t-1] + w1*x[2t] + w2*x[2t+1]
template <bool RELU>
__global__ __launch_bounds__(256)
void conv_big_s2(const float* __restrict__ x, const float* __restrict__ w,
                 const float* __restrict__ bias, float* __restrict__ y, int Ti) {
  constexpr int CI = 256;
  const int To = Ti >> 1;
  const int b = blockIdx.z;
  const int co0 = blockIdx.y * 128;
  const int t0 = blockIdx.x * 128;
  const int tid = threadIdx.x;
  const int tx = tid & 15, ty = tid >> 4;

  __shared__ float sW[16][3][132];
  __shared__ float sXe[16][144];  // sXe[ci][swz(u)] = x[ci, 2*(t0+u)],   u<128
  __shared__ float sXo[16][148];  // sXo[ci][swz(u)] = x[ci, 2*(t0+u)-1], u<129

  const float* xb = x + (size_t)b * CI * Ti;
  float acc[8][8];
#pragma unroll
  for (int i = 0; i < 8; i++)
#pragma unroll
    for (int j = 0; j < 8; j++) acc[i][j] = 0.f;

  const int be = swz(8 * tx);
  const int be8 = swz(8 * tx + 8);

  for (int cc = 0; cc < CI; cc += 16) {
    // stage W: 128 co rows x 48 floats (16ci x 3k) = 1536 float4
    for (int i = tid; i < 1536; i += 256) {
      const int co = i / 12, q = i - co * 12;
      const float4 v = *(const float4*)(w + (size_t)(co0 + co) * (CI * 3) + cc * 3 + q * 4);
      const float vv[4] = {v.x, v.y, v.z, v.w};
#pragma unroll
      for (int j = 0; j < 4; j++) {
        const int mm = q * 4 + j;
        const int ci = mm / 3, k = mm - ci * 3;
        sW[ci][k][co] = vv[j];
      }
    }
    // stage X even
    for (int i = tid; i < 16 * 128; i += 256) {
      const int ci = i >> 7, u = i & 127;
      sXe[ci][swz(u)] = xb[(size_t)(cc + ci) * Ti + 2 * (t0 + u)];
    }
    // stage X odd (left zero-pad only; right edge always in range)
    for (int i = tid; i < 16 * 129; i += 256) {
      const int ci = i / 129, u = i - ci * 129;
      const int t = 2 * (t0 + u) - 1;
      sXo[ci][swz(u)] = (t >= 0) ? xb[(size_t)(cc + ci) * Ti + t] : 0.f;
    }
    __syncthreads();

#pragma unroll 2
    for (int ci = 0; ci < 16; ci++) {
      float xe[8], xo[9], wv[8];
#pragma unroll
      for (int j = 0; j < 8; j++) xe[j] = sXe[ci][be + j];
#pragma unroll
      for (int j = 0; j < 8; j++) xo[j] = sXo[ci][be + j];
      xo[8] = sXo[ci][be8];
      // k=1 (even taps)
#pragma unroll
      for (int i = 0; i < 8; i++) wv[i] = sW[ci][1][8 * ty + i];
#pragma unroll
      for (int i = 0; i < 8; i++)
#pragma unroll
        for (int j = 0; j < 8; j++) acc[i][j] = fmaf(wv[i], xe[j], acc[i][j]);
      // k=0
#pragma unroll
      for (int i = 0; i < 8; i++) wv[i] = sW[ci][0][8 * ty + i];
#pragma unroll
      for (int i = 0; i < 8; i++)
#pragma unroll
        for (int j = 0; j < 8; j++) acc[i][j] = fmaf(wv[i], xo[j], acc[i][j]);
      // k=2
#pragma unroll
      for (int i = 0; i < 8; i++) wv[i] = sW[ci][2][8 * ty + i];
#pragma unroll
      for (int i = 0; i < 8; i++)
#pragma unroll
        for (int j = 0; j < 8; j++) acc[i][j] = fmaf(wv[i], xo[j + 1], acc[i][j]);
    }
    __syncthreads();
  }

#pragma unroll
  for (int i = 0; i < 8; i++) {
    const int co = co0 + 8 * ty + i;
    const float bv = bias[co];
    float* yp = y + ((size_t)b * 256 + co) * To + t0 + 8 * tx;
    float v[8];
#pragma unroll
    for (int j = 0; j < 8; j++) {
      const float s = acc[i][j] + bv;
      v[j] = RELU ? fmaxf(s, 0.f) : s;
    }
    ((float4*)yp)[0] = make_float4(v[0], v[1], v[2], v[3]);
    ((float4*)yp)[1] = make_float4(v[4], v[5], v[6], v[7]);
  }
}

// ---------------- stride-1 conv: tile 64co x 128t, 4x8 per thread ----------
template <int CI, bool RELU>
__global__ __launch_bounds__(256)
void conv_s1(const float* __restrict__ x, const float* __restrict__ w,
             const float* __restrict__ bias, float* __restrict__ y,
             int Ti, int Co) {
  const int b = blockIdx.z;
  const int co0 = blockIdx.y * 64;
  const int t0 = blockIdx.x * 128;
  const int tid = threadIdx.x;
  const int tx = tid & 15, ty = tid >> 4;

  __shared__ float sW[16][3][68];
  __shared__ float sX[16][148];  // sX[ci][swz(u)] = x[ci, t0+u-1], u<130

  const float* xb = x + (size_t)b * CI * Ti;
  float acc[4][8];
#pragma unroll
  for (int i = 0; i < 4; i++)
#pragma unroll
    for (int j = 0; j < 8; j++) acc[i][j] = 0.f;

  const int be = swz(8 * tx);
  const int be8 = swz(8 * tx + 8);

  for (int cc = 0; cc < CI; cc += 16) {
    for (int i = tid; i < 768; i += 256) {
      const int co = i / 12, q = i - co * 12;
      const float4 v = *(const float4*)(w + (size_t)(co0 + co) * (CI * 3) + cc * 3 + q * 4);
      const float vv[4] = {v.x, v.y, v.z, v.w};
#pragma unroll
      for (int j = 0; j < 4; j++) {
        const int mm = q * 4 + j;
        const int ci = mm / 3, k = mm - ci * 3;
        sW[ci][k][co] = vv[j];
      }
    }
    for (int i = tid; i < 16 * 130; i += 256) {
      const int ci = i / 130, u = i - ci * 130;
      const int t = t0 + u - 1;
      sX[ci][swz(u)] = (t >= 0 && t < Ti) ? xb[(size_t)(cc + ci) * Ti + t] : 0.f;
    }
    __syncthreads();

#pragma unroll 2
    for (int ci = 0; ci < 16; ci++) {
      float xw[10], wv[4];
#pragma unroll
      for (int j = 0; j < 8; j++) xw[j] = sX[ci][be + j];
      xw[8] = sX[ci][be8];
      xw[9] = sX[ci][be8 + 1];
#pragma unroll
      for (int k = 0; k < 3; k++) {
#pragma unroll
        for (int i = 0; i < 4; i++) wv[i] = sW[ci][k][4 * ty + i];
#pragma unroll
        for (int i = 0; i < 4; i++)
#pragma unroll
          for (int j = 0; j < 8; j++) acc[i][j] = fmaf(wv[i], xw[j + k], acc[i][j]);
      }
    }
    __syncthreads();
  }

#pragma unroll
  for (int i = 0; i < 4; i++) {
    const int co = co0 + 4 * ty + i;
    const float bv = bias[co];
    float* yp = y + ((size_t)b * Co + co) * Ti + t0 + 8 * tx;
    float v[8];
#pragma unroll
    for (int j = 0; j < 8; j++) {
      const float s = acc[i][j] + bv;
      v[j] = RELU ? fmaxf(s, 0.f) : s;
    }
    ((float4*)yp)[0] = make_float4(v[0], v[1], v[2], v[3]);
    ((float4*)yp)[1] = make_float4(v[4], v[5], v[6], v[7]);
  }
}

// ---------------- transposed conv s=2: Ci=Co=256 ----------------
// y[2u]   = sum_ci w1[co,ci]*x[ci,u]
// y[2u+1] = sum_ci w0[co,ci]*x[ci,u] + w2[co,ci]*x[ci,u+1]   (x[Tin]=0)
// tile 64co x 128u (=256 t out), 4co x 8u x {even,odd} per thread
template <bool RELU>
__global__ __launch_bounds__(256)
void convt_s2(const float* __restrict__ x, const float* __restrict__ w,
              const float* __restrict__ bias, float* __restrict__ y, int Tin) {
  constexpr int CI = 256;
  const int To = Tin * 2;
  const int b = blockIdx.z;
  const int co0 = blockIdx.y * 64;
  const int u0 = blockIdx.x * 128;
  const int tid = threadIdx.x;
  const int tx = tid & 15, ty = tid >> 4;

  __shared__ float sW[16][3][68];
  __shared__ float sX[16][148];  // sX[ci][swz(u)] = x[ci, u0+u], u<129

  const float* xb = x + (size_t)b * CI * Tin;
  float acce[4][8], acco[4][8];
#pragma unroll
  for (int i = 0; i < 4; i++)
#pragma unroll
    for (int j = 0; j < 8; j++) { acce[i][j] = 0.f; acco[i][j] = 0.f; }

  const int be = swz(8 * tx);
  const int be8 = swz(8 * tx + 8);

  for (int cc = 0; cc < CI; cc += 16) {
    for (int i = tid; i < 768; i += 256) {
      const int co = i / 12, q = i - co * 12;
      const float4 v = *(const float4*)(w + (size_t)(co0 + co) * (CI * 3) + cc * 3 + q * 4);
      const float vv[4] = {v.x, v.y, v.z, v.w};
#pragma unroll
      for (int j = 0; j < 4; j++) {
        const int mm = q * 4 + j;
        const int ci = mm / 3, k = mm - ci * 3;
        sW[ci][k][co] = vv[j];
      }
    }
    for (int i = tid; i < 16 * 129; i += 256) {
      const int ci = i / 129, u = i - ci * 129;
      const int t = u0 + u;
      sX[ci][swz(u)] = (t < Tin) ? xb[(size_t)(cc + ci) * Tin + t] : 0.f;
    }
    __syncthreads();

#pragma unroll 2
    for (int ci = 0; ci < 16; ci++) {
      float xw[9], wv[4];
#pragma unroll
      for (int j = 0; j < 8; j++) xw[j] = sX[ci][be + j];
      xw[8] = sX[ci][be8];
      // even outputs: k=1
#pragma unroll
      for (int i = 0; i < 4; i++) wv[i] = sW[ci][1][4 * ty + i];
#pragma unroll
      for (int i = 0; i < 4; i++)
#pragma unroll
        for (int j = 0; j < 8; j++) acce[i][j] = fmaf(wv[i], xw[j], acce[i][j]);
      // odd outputs: k=0
#pragma unroll
      for (int i = 0; i < 4; i++) wv[i] = sW[ci][0][4 * ty + i];
#pragma unroll
      for (int i = 0; i < 4; i++)
#pragma unroll
        for (int j = 0; j < 8; j++) acco[i][j] = fmaf(wv[i], xw[j], acco[i][j]);
      // odd outputs: k=2
#pragma unroll
      for (int i = 0; i < 4; i++) wv[i] = sW[ci][2][4 * ty + i];
#pragma unroll
      for (int i = 0; i < 4; i++)
#pragma unroll
        for (int j = 0; j < 8; j++) acco[i][j] = fmaf(wv[i], xw[j + 1], acco[i][j]);
    }
    __syncthreads();
  }

#pragma unroll
  for (int i = 0; i < 4; i++) {
    const int co = co0 + 4 * ty + i;
    const float bv = bias[co];
    float* yp = y + ((size_t)b * 256 + co) * To + 2 * (u0 + 8 * tx);
    float e[8], o[8];
#pragma unroll
    for (int j = 0; j < 8; j++) {
      float se = acce[i][j] + bv, so = acco[i][j] + bv;
      if (RELU) { se = fmaxf(se, 0.f); so = fmaxf(so, 0.f); }
      e[j] = se; o[j] = so;
    }
    ((float4*)yp)[0] = make_float4(e[0], o[0], e[1], o[1]);
    ((float4*)yp)[1] = make_float4(e[2], o[2], e[3], o[3]);
    ((float4*)yp)[2] = make_float4(e[4], o[4], e[5], o[5]);
    ((float4*)yp)[3] = make_float4(e[6], o[6], e[7], o[7]);
  }
}

// ---------------- codebook norms ----------------
__global__ __launch_bounds__(256)
void cnorm_kernel(const float* __restrict__ cb, float* __restrict__ cn) {
  const int c = blockIdx.x * 256 + threadIdx.x;  // K=512, grid=2
  const float* p = cb + (size_t)c * 64;
  float s = 0.f;
#pragma unroll
  for (int d = 0; d < 64; d++) s = fmaf(p[d], p[d], s);
  cn[c] = s;
}

// ---------------- VQ nearest-code + gather ----------------
// block: 64 t values of one batch; 256 threads = 64 t x 4 code groups of 128
__global__ __launch_bounds__(256)
void vq_kernel(const float* __restrict__ z, const float* __restrict__ cb,
               const float* __restrict__ cn, float* __restrict__ st) {
  const int Tl = 2048;
  const int b = blockIdx.y, t0 = blockIdx.x * 64;
  const int tid = threadIdx.x, tt = tid & 63, g = tid >> 6;

  __shared__ float zs[64][65];  // [d][t]
  for (int i = tid; i < 4096; i += 256) {
    const int d = i >> 6, t = i & 63;
    zs[d][t] = z[((size_t)b * 64 + d) * Tl + t0 + t];
  }
  __syncthreads();

  float zr[64];
#pragma unroll
  for (int d = 0; d < 64; d++) zr[d] = zs[d][tt];

  float best = 3.4e38f;
  int bidx = 0;
  const float* cp = cb + (size_t)g * 128 * 64;
  for (int c = 0; c < 128; c++) {
    const float4* c4 = (const float4*)(cp + (size_t)c * 64);
    float acc = 0.f;
#pragma unroll
    for (int q = 0; q < 16; q++) {
      const float4 v = c4[q];
      acc = fmaf(zr[4 * q + 0], v.x, acc);
      acc = fmaf(zr[4 * q + 1], v.y, acc);
      acc = fmaf(zr[4 * q + 2], v.z, acc);
      acc = fmaf(zr[4 * q + 3], v.w, acc);
    }
    const float dist = cn[g * 128 + c] - 2.f * acc;  // |c|^2 - 2 z.c
    if (dist < best) { best = dist; bidx = g * 128 + c; }
  }

  __shared__ float bd[4][64];
  __shared__ int bi[4][64];
  __shared__ int widx[64];
  bd[g][tt] = best;
  bi[g][tt] = bidx;
  __syncthreads();
  if (tid < 64) {
    float bb = bd[0][tid];
    int ii = bi[0][tid];
#pragma unroll
    for (int g2 = 1; g2 < 4; g2++) {
      if (bd[g2][tid] < bb) { bb = bd[g2][tid]; ii = bi[g2][tid]; }
    }
    widx[tid] = ii;
  }
  __syncthreads();
  // st = q = codebook[idx]  (z + stop_grad(q-z) == q in forward)
  for (int i = tid; i < 4096; i += 256) {
    const int d = i >> 6, t = i & 63;
    st[((size_t)b * 64 + d) * Tl + t0 + t] = cb[(size_t)widx[t] * 64 + d];
  }
}

// ---------------------------------------------------------------------------
extern "C" void kernel_launch(void* const* d_in, const int* in_sizes, int n_in,
                              void* d_out, int out_size, void* d_ws, size_t ws_size,
                              hipStream_t stream) {
  const float* inputs    = (const float*)d_in[0];
  const float* enc_w_in  = (const float*)d_in[1];
  const float* enc_b_in  = (const float*)d_in[2];
  const float* enc_ws_p  = (const float*)d_in[3];
  const float* enc_bs_p  = (const float*)d_in[4];
  const float* enc_w_out = (const float*)d_in[5];
  const float* enc_b_out = (const float*)d_in[6];
  const float* codebook  = (const float*)d_in[7];
  const float* dec_w_in  = (const float*)d_in[8];
  const float* dec_b_in  = (const float*)d_in[9];
  const float* dec_ws_p  = (const float*)d_in[10];
  const float* dec_bs_p  = (const float*)d_in[11];
  const float* dec_w_out = (const float*)d_in[12];
  const float* dec_b_out = (const float*)d_in[13];
  float* out = (float*)d_out;
  float* ws = (float*)d_ws;

  const int T = 32768, H = 256;
  const size_t PB = 8126464;  // fp32 elements of workspace per batch

  // batch-group size chosen from ws_size (deterministic across calls)
  int Bg = 16;
  while (Bg > 1 && (PB * (size_t)Bg * 4 + 2048) > ws_size) Bg >>= 1;
  const int groups = 16 / Bg;

  float* cnorm = ws + PB * (size_t)Bg;
  float* A0 = ws;                              // enc0 out [Bg,256,16384]
  float* A1 = ws + (size_t)4194304 * Bg;       // enc1 out [Bg,256,8192]
  float* A2 = ws + (size_t)6291456 * Bg;       // enc2 out [Bg,256,4096]
  float* A3 = ws + (size_t)7340032 * Bg;       // enc3 out [Bg,256,2048]
  float* Z  = ws + (size_t)7864320 * Bg;       // z  [Bg,64,2048]
  float* ST = ws + (size_t)7995392 * Bg;       // st [Bg,64,2048]
  float* B0 = ws;                              // dec_in out [Bg,256,2048]
  float* B1 = ws + (size_t)524288 * Bg;        // [Bg,256,4096]
  float* B2 = ws + (size_t)1572864 * Bg;       // [Bg,256,8192]
  float* B3 = ws + (size_t)3670016 * Bg;       // [Bg,256,16384]

  cnorm_kernel<<<dim3(2), dim3(256), 0, stream>>>(codebook, cnorm);

  for (int gr = 0; gr < groups; gr++) {
    const float* xg = inputs + (size_t)gr * Bg * T;
    float* outg = out + (size_t)gr * Bg * H * T;

    enc0_kernel<<<dim3(16, 256, Bg), 256, 0, stream>>>(xg, enc_w_in, enc_b_in, A0, T);
    conv_big_s2<true><<<dim3(64, 2, Bg), 256, 0, stream>>>(A0, enc_ws_p + 0 * 196608, enc_bs_p + 0 * H, A1, 16384);
    conv_big_s2<true><<<dim3(32, 2, Bg), 256, 0, stream>>>(A1, enc_ws_p + 1 * 196608, enc_bs_p + 1 * H, A2, 8192);
    conv_big_s2<true><<<dim3(16, 2, Bg), 256, 0, stream>>>(A2, enc_ws_p + 2 * 196608, enc_bs_p + 2 * H, A3, 4096);
    conv_s1<256, false><<<dim3(16, 1, Bg), 256, 0, stream>>>(A3, enc_w_out, enc_b_out, Z, 2048, 64);
    vq_kernel<<<dim3(32, Bg), 256, 0, stream>>>(Z, codebook, cnorm, ST);
    conv_s1<64, true><<<dim3(16, 4, Bg), 256, 0, stream>>>(ST, dec_w_in, dec_b_in, B0, 2048, 256);
    convt_s2<true><<<dim3(16, 4, Bg), 256, 0, stream>>>(B0, dec_ws_p + 0 * 196608, dec_bs_p + 0 * H, B1, 2048);
    convt_s2<true><<<dim3(32, 4, Bg), 256, 0, stream>>>(B1, dec_ws_p + 1 * 196608, dec_bs_p + 1 * H, B2, 4096);
    convt_s2<true><<<dim3(64, 4, Bg), 256, 0, stream>>>(B2, dec_ws_p + 2 * 196608, dec_bs_p + 2 * H, B3, 8192);
    convt_s2<false><<<dim3(128, 4, Bg), 256, 0, stream>>>(B3, dec_w_out, dec_b_out, outg, 16384);
  }
}